// Round 10
// baseline (261.865 us; speedup 1.0000x reference)
//
#include <hip/hip_runtime.h>
#include <hip/hip_bf16.h>
#include <stdint.h>
#include <math.h>

// GCN forward, collapsed to scalar form (W1:[1,16], W2:[16,1] are rank-1).
// R19: TWO-LEVEL PARTITION — eliminate random val[] gathers entirely.
// Evidence R10-R18: 4.2cy per divergent 4B gather invariant across Occ
// 35-61%, MLP 4-32, L1-bypass -> hard per-CU rate; only fix is structural.
// New: k_part2 re-bins each dst-bucket's edges by src-slice (8192 nodes,
// slice=src>>13; edge recoded dst_lo11 | src_lo13<<11). k_scat2 block
// (slice s, bucket p) stages val[s*8192..] in LDS (32KB, coalesced, L2-hot)
// + 8KB dst bins -> 2 LDS ops/edge, zero random global. k_deg3 streams
// slots2 coalesced (replaces latency-bound k_deg2). Predict scat 44.7->~12,
// deg 44-hidden->~6, +part2 ~12; total 221 -> ~155-175.
// R18: k_part wave-0 shfl scan. R12/R13: BPC=1024, CAP=208, tile-sort.
// No global atomics for accumulation (R2-R4: memory-side RMW ~20G/s).
// Dropout reproduces JAX partitionable threefry.
// Requires N <= 131072 (NBMAX) and N < 2^21 (src fits 21 bits).

#define KEEP_P 0.4f
#define RANGE 2048
#define SHIFT 11
#define MASK 2047
#define BPC 1024        // partition blocks
#define NBMAX 64
#define TILE 2048       // edges per k_part tile
#define TILE4 (TILE / 4)
#define G16 16          // pblk segments per k_part2 block
#define ST2 3456        // k_part2 stage capacity >= G16*CAP(208)
#define SL 8192         // src-slice width (2^13)

__host__ __device__ inline unsigned rotl32(unsigned v, int s) {
  return (v << s) | (v >> (32 - s));
}

__host__ __device__ inline void threefry2x32(unsigned key0, unsigned key1,
                                             unsigned x0, unsigned x1,
                                             unsigned& o0, unsigned& o1) {
  unsigned ks0 = key0, ks1 = key1, ks2 = key0 ^ key1 ^ 0x1BD11BDAu;
  unsigned v0 = x0 + ks0, v1 = x1 + ks1;
#define TF_R(r) { v0 += v1; v1 = rotl32(v1, r); v1 ^= v0; }
  TF_R(13) TF_R(15) TF_R(26) TF_R(6)
  v0 += ks1; v1 += ks2 + 1u;
  TF_R(17) TF_R(29) TF_R(16) TF_R(24)
  v0 += ks2; v1 += ks0 + 2u;
  TF_R(13) TF_R(15) TF_R(26) TF_R(6)
  v0 += ks0; v1 += ks1 + 3u;
  TF_R(17) TF_R(29) TF_R(16) TF_R(24)
  v0 += ks1; v1 += ks2 + 4u;
  TF_R(13) TF_R(15) TF_R(26) TF_R(6)
  v0 += ks2; v1 += ks0 + 5u;
#undef TF_R
  o0 = v0; o1 = v1;
}

__device__ inline float u01_from_bits(unsigned bits) {
  return __uint_as_float((bits >> 9) | 0x3f800000u) - 1.0f;
}

// ---- K1: slot partition (dst-bucket) with LDS tile-sort staging ------------
__global__ __launch_bounds__(256) void k_part(
    const int* __restrict__ src, const int* __restrict__ dst,
    unsigned* __restrict__ slots, unsigned* __restrict__ cnt,
    int NB, int CAP, int e4, int E,
    unsigned* __restrict__ cur2, int nz) {
  __shared__ unsigned hist[NBMAX], scan_s[NBMAX + 1], off[NBMAX];
  __shared__ unsigned tbase[NBMAX], cur[NBMAX];
  __shared__ unsigned stage[TILE];
  __shared__ unsigned char stage_p[TILE];
  const int tid = threadIdx.x;
  // zero k_part2's global cursors (used only after this kernel completes)
  if (blockIdx.x == 0)
    for (int i = tid; i < nz; i += 256) cur2[i] = 0u;
  const size_t blkbase = (size_t)blockIdx.x * NB;
  unsigned* myslots = slots + blkbase * CAP;
  for (int p = tid; p < NB; p += 256) cur[p] = (unsigned)(p * CAP);
  const int chunk = (e4 + BPC - 1) / BPC;
  const int j0 = blockIdx.x * chunk;
  const int j1 = min(j0 + chunk, e4);
  const int4* dst4 = reinterpret_cast<const int4*>(dst);
  const int4* src4 = reinterpret_cast<const int4*>(src);

  for (int t0 = j0; t0 < j1; t0 += TILE4) {
    __syncthreads();
    for (int p = tid; p < NB; p += 256) hist[p] = 0u;
    __syncthreads();
    // A: count this tile (hold dst in regs)
    const int ja = t0 + tid, jb = t0 + TILE4 / 2 + tid;
    const bool va = ja < j1 && tid < TILE4 / 2;
    const bool vb = jb < j1;
    int4 da, db;
    if (va) {
      da = dst4[ja];
      atomicAdd(&hist[(unsigned)da.x >> SHIFT], 1u);
      atomicAdd(&hist[(unsigned)da.y >> SHIFT], 1u);
      atomicAdd(&hist[(unsigned)da.z >> SHIFT], 1u);
      atomicAdd(&hist[(unsigned)da.w >> SHIFT], 1u);
    }
    if (vb) {
      db = dst4[jb];
      atomicAdd(&hist[(unsigned)db.x >> SHIFT], 1u);
      atomicAdd(&hist[(unsigned)db.y >> SHIFT], 1u);
      atomicAdd(&hist[(unsigned)db.z >> SHIFT], 1u);
      atomicAdd(&hist[(unsigned)db.w >> SHIFT], 1u);
    }
    __syncthreads();
    // B: wave-0 parallel scan (NB <= 64 lanes) + off/tbase/cur setup fused
    if (tid < 64) {
      unsigned h = (tid < NB) ? hist[tid] : 0u;
      unsigned inc = h;
#pragma unroll
      for (int d = 1; d < 64; d <<= 1) {
        unsigned t = __shfl_up(inc, d, 64);
        if (tid >= d) inc += t;
      }
      if (tid < NB) {
        unsigned ex = inc - h;
        scan_s[tid] = ex;
        off[tid] = ex;
        tbase[tid] = cur[tid];
        cur[tid] += h;
      }
      if (tid == NB - 1) scan_s[NB] = inc;
    }
    __syncthreads();
    // C: stage sorted-by-bucket
#define STAGE1(d, s) { unsigned ud = (unsigned)(d), us = (unsigned)(s); \
    unsigned p = ud >> SHIFT; unsigned pos = atomicAdd(&off[p], 1u); \
    stage[pos] = (ud & MASK) | (us << SHIFT); stage_p[pos] = (unsigned char)p; }
    if (va) {
      int4 sa = src4[ja];
      STAGE1(da.x, sa.x) STAGE1(da.y, sa.y) STAGE1(da.z, sa.z) STAGE1(da.w, sa.w)
    }
    if (vb) {
      int4 sb = src4[jb];
      STAGE1(db.x, sb.x) STAGE1(db.y, sb.y) STAGE1(db.z, sb.z) STAGE1(db.w, sb.w)
    }
#undef STAGE1
    __syncthreads();
    // D: write out bucket-contiguous runs
    const int tc = (int)scan_s[NB];
    for (int i = tid; i < tc; i += 256) {
      unsigned p = stage_p[i];
      myslots[tbase[p] + ((unsigned)i - scan_s[p])] = stage[i];
    }
  }
  __syncthreads();
  if (blockIdx.x == 0) {  // tail when E%4 != 0 (dead for E=6.4M)
    for (int t = e4 * 4 + tid; t < E; t += 256) {
      unsigned ud = (unsigned)dst[t], us = (unsigned)src[t];
      unsigned p = ud >> SHIFT;
      unsigned pos = atomicAdd(&cur[p], 1u);
      myslots[pos] = (ud & MASK) | (us << SHIFT);
    }
  }
  __syncthreads();
  for (int p = tid; p < NB; p += 256)
    cnt[blkbase + p] = cur[p] - (unsigned)(p * CAP);
}

// ---- K2: second-level partition: re-bin bucket p's edges by src-slice ------
// block (p, g): 16 pblk segments of bucket p -> slots2[p][slice] runs.
__global__ __launch_bounds__(256) void k_part2(
    const unsigned* __restrict__ slots, const unsigned* __restrict__ cnt,
    unsigned* __restrict__ slots2, unsigned* __restrict__ cur2,
    int NB, int CAP, int NS, int CAP2) {
  __shared__ unsigned raw[ST2], stage[ST2];
  __shared__ unsigned char tagp[ST2];
  __shared__ unsigned lens_s[G16], offs_s[G16];
  __shared__ unsigned hist[16], scan_s[16], off[16], gbase[16];
  __shared__ unsigned tc_s;
  const int tid = threadIdx.x, wv = tid >> 6, lane = tid & 63;
  const int p = blockIdx.x, g = blockIdx.y;
  if (tid < 16) hist[tid] = 0u;
  if (tid < 64) {
    unsigned ln = 0;
    if (lane < G16) {
      int b = g * G16 + lane;
      ln = cnt[(size_t)b * NB + p];
      if (ln > (unsigned)CAP) ln = (unsigned)CAP;
      lens_s[lane] = ln;
    }
    unsigned inc = ln;
#pragma unroll
    for (int d = 1; d < 16; d <<= 1) {
      unsigned t = __shfl_up(inc, d, 64);
      if (lane >= d) inc += t;
    }
    if (lane < G16) offs_s[lane] = inc - ln;
    if (lane == G16 - 1) tc_s = inc;
  }
  __syncthreads();
  // load 16 segments into raw[]; wave wv handles segs 4wv..4wv+3 (coalesced)
  for (int k = 0; k < 4; ++k) {
    const int j = 4 * wv + k;
    const unsigned len = lens_s[j], off0 = offs_s[j];
    const unsigned* e = slots + ((size_t)(g * G16 + j) * NB + p) * CAP;
    for (unsigned i = lane; i < len; i += 64) raw[off0 + i] = e[i];
  }
  __syncthreads();
  const int TC = (int)tc_s;
  for (int i = tid; i < TC; i += 256)
    atomicAdd(&hist[raw[i] >> 24], 1u);   // slice = src>>13 = v>>24
  __syncthreads();
  if (tid < 64) {
    unsigned h = (lane < NS) ? hist[lane] : 0u;
    unsigned inc = h;
#pragma unroll
    for (int d = 1; d < 16; d <<= 1) {
      unsigned t = __shfl_up(inc, d, 64);
      if (lane >= d) inc += t;
    }
    if (lane < NS) {
      scan_s[lane] = inc - h;
      off[lane] = inc - h;
      gbase[lane] = atomicAdd(&cur2[p * NS + lane], h);
    }
  }
  __syncthreads();
  for (int i = tid; i < TC; i += 256) {
    unsigned v = raw[i];
    unsigned s = v >> 24;
    unsigned pos = atomicAdd(&off[s], 1u);
    // recode: dst_lo11 | src_lo13 << 11
    stage[pos] = (v & MASK) | (((v >> SHIFT) & (SL - 1)) << SHIFT);
    tagp[pos] = (unsigned char)s;
  }
  __syncthreads();
  for (int i = tid; i < TC; i += 256) {
    unsigned s = tagp[i];
    unsigned idx = gbase[s] + ((unsigned)i - scan_s[s]);
    if (idx < (unsigned)CAP2)
      slots2[(size_t)(p * NS + (int)s) * CAP2 + idx] = stage[i];
  }
}

// ---- K3: degree from slots2 (coalesced cell streams), u16-packed bins ------
__global__ __launch_bounds__(256) void k_deg3(
    const unsigned* __restrict__ slots2, const unsigned* __restrict__ cnt2,
    unsigned short* __restrict__ part16, int NB, int NS, int CAP2) {
  __shared__ unsigned bins[RANGE / 2];  // 4 KB
  const int tid = threadIdx.x;
  const int sh = blockIdx.x, p = blockIdx.y;
  const int s = sh >> 1, h = sh & 1;
  for (int i = tid; i < RANGE / 2; i += 256) bins[i] = 0u;
  __syncthreads();
  const int c = p * NS + s;
  int len = cnt2[c]; if (len > CAP2) len = CAP2;
  const unsigned* e = slots2 + (size_t)c * CAP2;
#define DEG_ONE(v) { unsigned r = (v) & MASK; \
    atomicAdd(&bins[r >> 1], 1u << ((r & 1) * 16)); }
  for (int i = (h * 256 + tid) * 4; i + 4 <= len; i += 2048) {
    uint4 u = *reinterpret_cast<const uint4*>(e + i);
    DEG_ONE(u.x) DEG_ONE(u.y) DEG_ONE(u.z) DEG_ONE(u.w)
  }
  if (h == 0 && tid < (len & 3)) DEG_ONE(e[(len & ~3) + tid])
#undef DEG_ONE
  __syncthreads();
  unsigned* my32 = (unsigned*)(part16 + ((size_t)sh * NB + p) * RANGE);
  for (int i = tid; i < RANGE / 2; i += 256) my32[i] = bins[i];
}

// ---- K4: reduce deg partials -> dinv; dropout1 -> y ------------------------
__global__ __launch_bounds__(256) void k_node1(
    const float* __restrict__ x, const unsigned short* __restrict__ part16,
    float* __restrict__ dinv, float* __restrict__ y,
    int NB, int np, int n, unsigned k1a, unsigned k1b) {
  int i = blockIdx.x * blockDim.x + threadIdx.x;
  if (i >= n) return;
  const int p = i >> SHIFT, r = i & MASK;
  unsigned d = 0;
  for (int b = 0; b < np; ++b)
    d += part16[((size_t)b * NB + p) * RANGE + r];
  float di = (d > 0) ? (1.0f / sqrtf((float)d)) : 0.0f;
  dinv[i] = di;
  unsigned o0, o1;
  threefry2x32(k1a, k1b, 0u, (unsigned)i, o0, o1);
  float u = u01_from_bits(o0 ^ o1);   // partitionable 32-bit bits = out0 ^ out1
  float xd = (u < KEEP_P) ? (x[i] / KEEP_P) : 0.0f;
  y[i] = xd * di;
}

// ---- K5/K7: gather-free scatter: val slice in LDS + dst bins in LDS --------
__global__ __launch_bounds__(256) void k_scat2(
    const unsigned* __restrict__ slots2, const unsigned* __restrict__ cnt2,
    const float* __restrict__ val, float* __restrict__ part,
    int NB, int NS, int CAP2, int n) {
  __shared__ float vs[SL];       // 32 KB val slice
  __shared__ float bins[RANGE];  // 8 KB
  const int tid = threadIdx.x;
  const int sh = blockIdx.x, p = blockIdx.y;
  const int s = sh >> 1, h = sh & 1;
  const int base_n = s * SL;
  const int lim = n - base_n;
  if (lim >= SL) {
    const float4* v4 = reinterpret_cast<const float4*>(val + base_n);
    float4* s4 = reinterpret_cast<float4*>(vs);
    for (int i = tid; i < SL / 4; i += 256) s4[i] = v4[i];
  } else {
    for (int i = tid; i < SL; i += 256)
      vs[i] = (i < lim) ? val[base_n + i] : 0.0f;
  }
  for (int i = tid; i < RANGE; i += 256) bins[i] = 0.0f;
  __syncthreads();
  const int c = p * NS + s;
  int len = cnt2[c]; if (len > CAP2) len = CAP2;
  const unsigned* e = slots2 + (size_t)c * CAP2;
  for (int i = (h * 256 + tid) * 4; i + 4 <= len; i += 2048) {
    uint4 u = *reinterpret_cast<const uint4*>(e + i);
    float a0 = vs[u.x >> SHIFT], a1 = vs[u.y >> SHIFT];
    float a2 = vs[u.z >> SHIFT], a3 = vs[u.w >> SHIFT];
    atomicAdd(&bins[u.x & MASK], a0);
    atomicAdd(&bins[u.y & MASK], a1);
    atomicAdd(&bins[u.z & MASK], a2);
    atomicAdd(&bins[u.w & MASK], a3);
  }
  if (h == 0 && tid < (len & 3)) {
    unsigned v = e[(len & ~3) + tid];
    atomicAdd(&bins[v & MASK], vs[v >> SHIFT]);
  }
  __syncthreads();
  float* my = part + ((size_t)sh * NB + p) * RANGE;
  for (int i = tid; i < RANGE; i += 256) my[i] = bins[i];
}

// ---- K6: reduce s partials; layer1 epilogue + relu + dropout2 + W2 dot -----
__global__ __launch_bounds__(256) void k_node2(
    const float* __restrict__ part, const float* __restrict__ dinv,
    const float* __restrict__ W1, const float* __restrict__ b1,
    const float* __restrict__ W2, float* __restrict__ z2,
    int NB, int np, int n, unsigned k2a, unsigned k2b) {
  int i = blockIdx.x * blockDim.x + threadIdx.x;
  if (i >= n) return;
  const int p = i >> SHIFT, r = i & MASK;
  float s = 0.0f;
  for (int b = 0; b < np; ++b)
    s += part[((size_t)b * NB + p) * RANGE + r];
  float t = s * dinv[i];
  float z = 0.0f;
  unsigned base = (unsigned)i * 16u;
#pragma unroll
  for (int c = 0; c < 16; ++c) {
    float h = W1[c] * t + b1[c];
    h = fmaxf(h, 0.0f);
    unsigned o0, o1;
    threefry2x32(k2a, k2b, 0u, base + (unsigned)c, o0, o1);
    float u = u01_from_bits(o0 ^ o1);
    float hd = (u < KEEP_P) ? (h / KEEP_P) : 0.0f;
    z += hd * W2[c];
  }
  z2[i] = z * dinv[i];   // dinv[dst] factor applied in k_final
}

// ---- K8: final combine: out = b2 + dinv * sum(partials) --------------------
__global__ __launch_bounds__(256) void k_final(
    const float* __restrict__ part, const float* __restrict__ dinv,
    const float* __restrict__ b2, float* __restrict__ out,
    int NB, int np, int n) {
  int i = blockIdx.x * blockDim.x + threadIdx.x;
  if (i >= n) return;
  const int p = i >> SHIFT, r = i & MASK;
  float s = 0.0f;
  for (int b = 0; b < np; ++b)
    s += part[((size_t)b * NB + p) * RANGE + r];
  out[i] = b2[0] + dinv[i] * s;
}

extern "C" void kernel_launch(void* const* d_in, const int* in_sizes, int n_in,
                              void* d_out, int out_size, void* d_ws, size_t ws_size,
                              hipStream_t stream) {
  const float* x  = (const float*)d_in[0];
  const int* edge = (const int*)d_in[1];   // [2, E] int32
  const float* W1 = (const float*)d_in[2]; // [1,16]
  const float* b1 = (const float*)d_in[3]; // [16]
  const float* W2 = (const float*)d_in[4]; // [16,1]
  const float* b2 = (const float*)d_in[5]; // [1]
  float* out = (float*)d_out;              // [N,1] f32

  const int N = in_sizes[0];
  const int E = in_sizes[1] / 2;
  const int* src = edge;
  const int* dst = edge + E;

  const int NP = (N + 255) & ~255;
  const int NB = (N + RANGE - 1) / RANGE;   // 49 for N=100K (<= NBMAX)
  const int NS = (N + SL - 1) / SL;         // 13 src slices
  const int np2 = 2 * NS;                   // scatter partials (2 halves/slice)

  // cell capacity: lam + 7 sigma
  double lam2 = (double)E * (double)RANGE * (double)SL / ((double)N * (double)N);
  int CAP2 = (int)(lam2 + 7.0 * sqrt(lam2)) + 8;
  CAP2 = (CAP2 + 3) & ~3;

  // ws layout: [slots NB*BPC*CAP u32][cnt BPC*NB u32][cur2 NB*NS u32]
  //            [slots2 NB*NS*CAP2 u32][part np2*NB*RANGE f32 (aliases deg
  //            u16 partials)][dinv][y][z2]
  const size_t cnt_sz   = (size_t)BPC * NB * 4;
  const size_t cur2_sz  = ((size_t)NB * NS * 4 + 255) & ~(size_t)255;
  const size_t slots2_sz= (size_t)NB * NS * CAP2 * 4;
  const size_t part_sz  = (size_t)np2 * NB * RANGE * 4;
  const size_t small_sz = (size_t)3 * NP * 4;
  size_t fixed = cnt_sz + cur2_sz + slots2_sz + part_sz + small_sz + 1024;
  size_t avail = ws_size > fixed ? ws_size - fixed : 0;
  int CAP = (int)(avail / ((size_t)NB * BPC * 4));
  CAP &= ~3;                  // 16B-aligned slot starts for uint4 loads
  if (CAP > 208) CAP = 208;   // lam=128, +7sigma
  if (CAP < 176) CAP = 176;   // ws guard (should not trigger)

  char* w = (char*)d_ws;
  unsigned* slots  = (unsigned*)w;  w += (size_t)NB * BPC * CAP * 4;
  unsigned* cnt    = (unsigned*)w;  w += cnt_sz;
  w = (char*)(((uintptr_t)w + 255) & ~(uintptr_t)255);
  unsigned* cur2   = (unsigned*)w;  w += cur2_sz;
  unsigned* slots2 = (unsigned*)w;  w += slots2_sz;
  w = (char*)(((uintptr_t)w + 255) & ~(uintptr_t)255);
  float* part_f = (float*)w;
  unsigned short* part16 = (unsigned short*)w;  // aliased (deg phase ends first)
  w += part_sz;
  float* dinv = (float*)w;
  float* y    = dinv + NP;
  float* z2   = y + NP;

  // Dropout keys: foldlike split(key(42)) under partitionable threefry.
  unsigned k1a, k1b, k2a, k2b;
  threefry2x32(0u, 42u, 0u, 0u, k1a, k1b);
  threefry2x32(0u, 42u, 0u, 1u, k2a, k2b);

  const int e4 = E >> 2;
  const int gN = (N + 255) / 256;

  k_part <<<BPC, 256, 0, stream>>>(src, dst, slots, cnt, NB, CAP, e4, E,
                                   cur2, NB * NS);
  k_part2<<<dim3(NB, BPC / G16), 256, 0, stream>>>(slots, cnt, slots2, cur2,
                                                   NB, CAP, NS, CAP2);
  k_deg3 <<<dim3(np2, NB), 256, 0, stream>>>(slots2, cur2, part16, NB, NS, CAP2);
  k_node1<<<gN, 256, 0, stream>>>(x, part16, dinv, y, NB, np2, N, k1a, k1b);
  k_scat2<<<dim3(np2, NB), 256, 0, stream>>>(slots2, cur2, y, part_f,
                                             NB, NS, CAP2, N);
  k_node2<<<gN, 256, 0, stream>>>(part_f, dinv, W1, b1, W2, z2, NB, np2, N,
                                  k2a, k2b);
  k_scat2<<<dim3(np2, NB), 256, 0, stream>>>(slots2, cur2, z2, part_f,
                                             NB, NS, CAP2, N);
  k_final<<<gN, 256, 0, stream>>>(part_f, dinv, b2, out, NB, np2, N);
}

// Round 11
// 219.423 us; speedup vs baseline: 1.1934x; 1.1934x over previous
//
#include <hip/hip_runtime.h>
#include <hip/hip_bf16.h>
#include <stdint.h>

// GCN forward, collapsed to scalar form (W1:[1,16], W2:[16,1] are rank-1).
// R20: revert R19 two-level partition (FAILED: gather-free k_scat2 = 45.4us
// == gather k_scat 44.8 -> LAW: an E-touching LDS-histogram pass costs
// ~45us (~4.3cy/edge/CU) regardless of access pattern/occupancy/MLP; all
// pipes idle. 3 such passes (deg,scat1,scat2) are unfusable (strict chain
// deg->dinv->y->scat1->node2->scat2; per-src weight dinv[src] blocks all
// reorderings) => ~135us fixed + fill 40.6. Remaining slack: part+nodes+
// gaps ~45us). This round: BPC 1024->2048 — k_part was GRID-limited to
// 4 blocks/CU (LDS only 11KB); now 8/CU. lam=64, CAP=120 (+7sigma; R19
// proved ws>=100MB so 48MB slots fit). deg2/scat keep the R18 rhythm:
// SPW=16 run as 2 super-rounds of the proven 8-seg structure.
// Predict total 221.2 -> ~213-217; >=221 => revert BPC, R18 is the floor.
// R18: k_part wave-0 shfl scan. R13: 8-gathers-in-flight rhythm.
// No global atomics for accumulation (R2-R4: memory-side RMW ~20G/s).
// Dropout reproduces JAX partitionable threefry.
// Requires N <= 131072 (NBMAX) and N < 2^21 (src fits 21 bits).

#define KEEP_P 0.4f
#define RANGE 2048
#define SHIFT 11
#define MASK 2047
#define BPC 2048        // partition blocks (8 blocks/CU for k_part)
#define KS 32           // scatter slices (grid = KS x NB)
#define SEGS (BPC / KS) // 64 slot-segments per scatter block
#define SPW (SEGS / 4)  // 16 segments per wave (2 super-rounds of 8)
#define NBMAX 64
#define TILE 2048       // edges per k_part tile
#define TILE4 (TILE / 4)

__host__ __device__ inline unsigned rotl32(unsigned v, int s) {
  return (v << s) | (v >> (32 - s));
}

__host__ __device__ inline void threefry2x32(unsigned key0, unsigned key1,
                                             unsigned x0, unsigned x1,
                                             unsigned& o0, unsigned& o1) {
  unsigned ks0 = key0, ks1 = key1, ks2 = key0 ^ key1 ^ 0x1BD11BDAu;
  unsigned v0 = x0 + ks0, v1 = x1 + ks1;
#define TF_R(r) { v0 += v1; v1 = rotl32(v1, r); v1 ^= v0; }
  TF_R(13) TF_R(15) TF_R(26) TF_R(6)
  v0 += ks1; v1 += ks2 + 1u;
  TF_R(17) TF_R(29) TF_R(16) TF_R(24)
  v0 += ks2; v1 += ks0 + 2u;
  TF_R(13) TF_R(15) TF_R(26) TF_R(6)
  v0 += ks0; v1 += ks1 + 3u;
  TF_R(17) TF_R(29) TF_R(16) TF_R(24)
  v0 += ks1; v1 += ks2 + 4u;
  TF_R(13) TF_R(15) TF_R(26) TF_R(6)
  v0 += ks2; v1 += ks0 + 5u;
#undef TF_R
  o0 = v0; o1 = v1;
}

__device__ inline float u01_from_bits(unsigned bits) {
  return __uint_as_float((bits >> 9) | 0x3f800000u) - 1.0f;
}

// ---- K1: slot partition with LDS tile-sort staging -------------------------
__global__ __launch_bounds__(256) void k_part(
    const int* __restrict__ src, const int* __restrict__ dst,
    unsigned* __restrict__ slots, unsigned* __restrict__ cnt,
    int NB, int CAP, int e4, int E) {
  __shared__ unsigned hist[NBMAX], scan_s[NBMAX + 1], off[NBMAX];
  __shared__ unsigned tbase[NBMAX], cur[NBMAX];
  __shared__ unsigned stage[TILE];
  __shared__ unsigned char stage_p[TILE];
  const int tid = threadIdx.x;
  const size_t blkbase = (size_t)blockIdx.x * NB;
  unsigned* myslots = slots + blkbase * CAP;
  for (int p = tid; p < NB; p += 256) cur[p] = (unsigned)(p * CAP);
  const int chunk = (e4 + BPC - 1) / BPC;
  const int j0 = blockIdx.x * chunk;
  const int j1 = min(j0 + chunk, e4);
  const int4* dst4 = reinterpret_cast<const int4*>(dst);
  const int4* src4 = reinterpret_cast<const int4*>(src);

  for (int t0 = j0; t0 < j1; t0 += TILE4) {
    __syncthreads();
    for (int p = tid; p < NB; p += 256) hist[p] = 0u;
    __syncthreads();
    // A: count this tile (hold dst in regs)
    const int ja = t0 + tid, jb = t0 + TILE4 / 2 + tid;
    const bool va = ja < j1 && tid < TILE4 / 2;
    const bool vb = jb < j1;
    int4 da, db;
    if (va) {
      da = dst4[ja];
      atomicAdd(&hist[(unsigned)da.x >> SHIFT], 1u);
      atomicAdd(&hist[(unsigned)da.y >> SHIFT], 1u);
      atomicAdd(&hist[(unsigned)da.z >> SHIFT], 1u);
      atomicAdd(&hist[(unsigned)da.w >> SHIFT], 1u);
    }
    if (vb) {
      db = dst4[jb];
      atomicAdd(&hist[(unsigned)db.x >> SHIFT], 1u);
      atomicAdd(&hist[(unsigned)db.y >> SHIFT], 1u);
      atomicAdd(&hist[(unsigned)db.z >> SHIFT], 1u);
      atomicAdd(&hist[(unsigned)db.w >> SHIFT], 1u);
    }
    __syncthreads();
    // B: wave-0 parallel scan (NB <= 64 lanes) + off/tbase/cur setup fused
    if (tid < 64) {
      unsigned h = (tid < NB) ? hist[tid] : 0u;
      unsigned inc = h;
#pragma unroll
      for (int d = 1; d < 64; d <<= 1) {
        unsigned t = __shfl_up(inc, d, 64);
        if (tid >= d) inc += t;
      }
      if (tid < NB) {
        unsigned ex = inc - h;
        scan_s[tid] = ex;
        off[tid] = ex;
        tbase[tid] = cur[tid];
        cur[tid] += h;
      }
      if (tid == NB - 1) scan_s[NB] = inc;
    }
    __syncthreads();
    // C: stage sorted-by-bucket
#define STAGE1(d, s) { unsigned ud = (unsigned)(d), us = (unsigned)(s); \
    unsigned p = ud >> SHIFT; unsigned pos = atomicAdd(&off[p], 1u); \
    stage[pos] = (ud & MASK) | (us << SHIFT); stage_p[pos] = (unsigned char)p; }
    if (va) {
      int4 sa = src4[ja];
      STAGE1(da.x, sa.x) STAGE1(da.y, sa.y) STAGE1(da.z, sa.z) STAGE1(da.w, sa.w)
    }
    if (vb) {
      int4 sb = src4[jb];
      STAGE1(db.x, sb.x) STAGE1(db.y, sb.y) STAGE1(db.z, sb.z) STAGE1(db.w, sb.w)
    }
#undef STAGE1
    __syncthreads();
    // D: write out bucket-contiguous runs
    const int tc = (int)scan_s[NB];
    for (int i = tid; i < tc; i += 256) {
      unsigned p = stage_p[i];
      myslots[tbase[p] + ((unsigned)i - scan_s[p])] = stage[i];
    }
  }
  __syncthreads();
  if (blockIdx.x == 0) {  // tail when E%4 != 0 (dead for E=6.4M)
    for (int t = e4 * 4 + tid; t < E; t += 256) {
      unsigned ud = (unsigned)dst[t], us = (unsigned)src[t];
      unsigned p = ud >> SHIFT;
      unsigned pos = atomicAdd(&cur[p], 1u);
      myslots[pos] = (ud & MASK) | (us << SHIFT);
    }
  }
  __syncthreads();
  for (int p = tid; p < NB; p += 256)
    cnt[blkbase + p] = cur[p] - (unsigned)(p * CAP);
}

// helper macros shared by k_deg2 / k_scat ------------------------------------
#define LSEG8(sb0) \
  const unsigned* e0 = slots + ((size_t)((sb0) + 0) * NB + p) * CAP; \
  const int l0 = cnt[(size_t)((sb0) + 0) * NB + p]; \
  const unsigned* e1 = slots + ((size_t)((sb0) + 1) * NB + p) * CAP; \
  const int l1 = cnt[(size_t)((sb0) + 1) * NB + p]; \
  const unsigned* e2 = slots + ((size_t)((sb0) + 2) * NB + p) * CAP; \
  const int l2 = cnt[(size_t)((sb0) + 2) * NB + p]; \
  const unsigned* e3 = slots + ((size_t)((sb0) + 3) * NB + p) * CAP; \
  const int l3 = cnt[(size_t)((sb0) + 3) * NB + p]; \
  const unsigned* e4_ = slots + ((size_t)((sb0) + 4) * NB + p) * CAP; \
  const int l4 = cnt[(size_t)((sb0) + 4) * NB + p]; \
  const unsigned* e5 = slots + ((size_t)((sb0) + 5) * NB + p) * CAP; \
  const int l5 = cnt[(size_t)((sb0) + 5) * NB + p]; \
  const unsigned* e6 = slots + ((size_t)((sb0) + 6) * NB + p) * CAP; \
  const int l6 = cnt[(size_t)((sb0) + 6) * NB + p]; \
  const unsigned* e7 = slots + ((size_t)((sb0) + 7) * NB + p) * CAP; \
  const int l7 = cnt[(size_t)((sb0) + 7) * NB + p];

// tail bookkeeping: seg k tail starts at st_k = min(4*(l_k/4), 128)
// (CAP=120 < 128 so the 128 clamp never binds; tail = l%4 edges)
#define TAILPRE \
  const int st0 = (l0 >> 2 << 2) < 128 ? (l0 >> 2 << 2) : 128; \
  const int st1 = (l1 >> 2 << 2) < 128 ? (l1 >> 2 << 2) : 128; \
  const int st2 = (l2 >> 2 << 2) < 128 ? (l2 >> 2 << 2) : 128; \
  const int st3 = (l3 >> 2 << 2) < 128 ? (l3 >> 2 << 2) : 128; \
  const int st4 = (l4 >> 2 << 2) < 128 ? (l4 >> 2 << 2) : 128; \
  const int st5 = (l5 >> 2 << 2) < 128 ? (l5 >> 2 << 2) : 128; \
  const int st6 = (l6 >> 2 << 2) < 128 ? (l6 >> 2 << 2) : 128; \
  const int st7 = (l7 >> 2 << 2) < 128 ? (l7 >> 2 << 2) : 128; \
  const int q1 = (l0 - st0); \
  const int q2 = q1 + (l1 - st1); \
  const int q3 = q2 + (l2 - st2); \
  const int q4 = q3 + (l3 - st3); \
  const int q5 = q4 + (l4 - st4); \
  const int q6 = q5 + (l5 - st5); \
  const int q7 = q6 + (l6 - st6); \
  const int qT = q7 + (l7 - st7);

#define TAILSEL \
  const unsigned* es = e0; int st = st0; int pr = 0; \
  if (t >= q1) { es = e1; st = st1; pr = q1; } \
  if (t >= q2) { es = e2; st = st2; pr = q2; } \
  if (t >= q3) { es = e3; st = st3; pr = q3; } \
  if (t >= q4) { es = e4_; st = st4; pr = q4; } \
  if (t >= q5) { es = e5; st = st5; pr = q5; } \
  if (t >= q6) { es = e6; st = st6; pr = q6; } \
  if (t >= q7) { es = e7; st = st7; pr = q7; }

// ---- K2: degree from slots; 2 super-rounds of (2x(2 loads+8 atomics)+tail) -
__global__ __launch_bounds__(256) void k_deg2(
    const unsigned* __restrict__ slots, const unsigned* __restrict__ cnt,
    unsigned short* __restrict__ part16, int NB, int CAP) {
  __shared__ unsigned bins[RANGE / 2];  // 4 KB, u16-packed
  const int tid = threadIdx.x, w = tid >> 6, lane = tid & 63;
  const int p = blockIdx.y, kd = blockIdx.x;
  for (int i = tid; i < RANGE / 2; i += 256) bins[i] = 0u;
  __syncthreads();
  const int half = lane >> 5, li = lane & 31, i4 = 4 * li;
#define DEG_ONE(v) { unsigned r = (v) & MASK; \
    atomicAdd(&bins[r >> 1], 1u << ((r & 1) * 16)); }
  for (int sr = 0; sr < SPW / 8; ++sr) {
    LSEG8(kd * SEGS + w * SPW + 8 * sr)
    // round 1: segs {0,1} and {2,3} via lane-half divergent bases
    {
      const unsigned* eA = half ? e1 : e0; const int lA = half ? l1 : l0;
      const unsigned* eB = half ? e3 : e2; const int lB = half ? l3 : l2;
      const bool fA = i4 + 4 <= lA, fB = i4 + 4 <= lB;
      uint4 uA, uB;
      if (fA) uA = *reinterpret_cast<const uint4*>(eA + i4);
      if (fB) uB = *reinterpret_cast<const uint4*>(eB + i4);
      if (fA) { DEG_ONE(uA.x) DEG_ONE(uA.y) DEG_ONE(uA.z) DEG_ONE(uA.w) }
      if (fB) { DEG_ONE(uB.x) DEG_ONE(uB.y) DEG_ONE(uB.z) DEG_ONE(uB.w) }
    }
    // round 2: segs {4,5} and {6,7}
    {
      const unsigned* eA = half ? e5 : e4_; const int lA = half ? l5 : l4;
      const unsigned* eB = half ? e7 : e6;  const int lB = half ? l7 : l6;
      const bool fA = i4 + 4 <= lA, fB = i4 + 4 <= lB;
      uint4 uA, uB;
      if (fA) uA = *reinterpret_cast<const uint4*>(eA + i4);
      if (fB) uB = *reinterpret_cast<const uint4*>(eB + i4);
      if (fA) { DEG_ONE(uA.x) DEG_ONE(uA.y) DEG_ONE(uA.z) DEG_ONE(uA.w) }
      if (fB) { DEG_ONE(uB.x) DEG_ONE(uB.y) DEG_ONE(uB.z) DEG_ONE(uB.w) }
    }
    // cooperative tail over these 8 segs' [st, l) regions
    TAILPRE
    for (int t = lane; t < qT; t += 64) {
      TAILSEL
      DEG_ONE(es[st + t - pr])
    }
  }
#undef DEG_ONE
  __syncthreads();
  unsigned* my32 = (unsigned*)(part16 + ((size_t)kd * gridDim.y + p) * RANGE);
  for (int i = tid; i < RANGE / 2; i += 256) my32[i] = bins[i];
}

// ---- K3: reduce deg partials -> dinv; dropout1 -> y ------------------------
__global__ __launch_bounds__(256) void k_node1(
    const float* __restrict__ x, const unsigned short* __restrict__ part16,
    float* __restrict__ dinv, float* __restrict__ y,
    int NB, int n, unsigned k1a, unsigned k1b) {
  int i = blockIdx.x * blockDim.x + threadIdx.x;
  if (i >= n) return;
  const int p = i >> SHIFT, r = i & MASK;
  unsigned d = 0;
  for (int b = 0; b < KS; ++b)
    d += part16[((size_t)b * NB + p) * RANGE + r];
  float di = (d > 0) ? (1.0f / sqrtf((float)d)) : 0.0f;
  dinv[i] = di;
  unsigned o0, o1;
  threefry2x32(k1a, k1b, 0u, (unsigned)i, o0, o1);
  float u = u01_from_bits(o0 ^ o1);   // partitionable 32-bit bits = out0 ^ out1
  float xd = (u < KEEP_P) ? (x[i] / KEEP_P) : 0.0f;
  y[i] = xd * di;
}

// ---- K4/K6: binned scatter; 2 super-rounds of the R13 rhythm ---------------
__global__ __launch_bounds__(256) void k_scat(
    const unsigned* __restrict__ slots, const unsigned* __restrict__ cnt,
    const float* __restrict__ val, float* __restrict__ part,
    int NB, int CAP) {
  __shared__ float bins[RANGE];  // 8 KB
  const int tid = threadIdx.x, w = tid >> 6, lane = tid & 63;
  const int p = blockIdx.y, ks = blockIdx.x;
  for (int i = tid; i < RANGE; i += 256) bins[i] = 0.0f;
  __syncthreads();
  const int half = lane >> 5, li = lane & 31, i4 = 4 * li;
  for (int sr = 0; sr < SPW / 8; ++sr) {
    LSEG8(ks * SEGS + w * SPW + 8 * sr)
    // round 1: segs {0,1} and {2,3}; 2 loads + 8 gathers in flight
    {
      const unsigned* eA = half ? e1 : e0; const int lA = half ? l1 : l0;
      const unsigned* eB = half ? e3 : e2; const int lB = half ? l3 : l2;
      const bool fA = i4 + 4 <= lA, fB = i4 + 4 <= lB;
      uint4 uA, uB;
      if (fA) uA = *reinterpret_cast<const uint4*>(eA + i4);
      if (fB) uB = *reinterpret_cast<const uint4*>(eB + i4);
      float a0, a1, a2, a3, c0, c1, c2, c3;
      if (fA) {
        a0 = val[uA.x >> SHIFT]; a1 = val[uA.y >> SHIFT];
        a2 = val[uA.z >> SHIFT]; a3 = val[uA.w >> SHIFT];
      }
      if (fB) {
        c0 = val[uB.x >> SHIFT]; c1 = val[uB.y >> SHIFT];
        c2 = val[uB.z >> SHIFT]; c3 = val[uB.w >> SHIFT];
      }
      if (fA) {
        atomicAdd(&bins[uA.x & MASK], a0);
        atomicAdd(&bins[uA.y & MASK], a1);
        atomicAdd(&bins[uA.z & MASK], a2);
        atomicAdd(&bins[uA.w & MASK], a3);
      }
      if (fB) {
        atomicAdd(&bins[uB.x & MASK], c0);
        atomicAdd(&bins[uB.y & MASK], c1);
        atomicAdd(&bins[uB.z & MASK], c2);
        atomicAdd(&bins[uB.w & MASK], c3);
      }
    }
    // round 2: segs {4,5} and {6,7}
    {
      const unsigned* eA = half ? e5 : e4_; const int lA = half ? l5 : l4;
      const unsigned* eB = half ? e7 : e6;  const int lB = half ? l7 : l6;
      const bool fA = i4 + 4 <= lA, fB = i4 + 4 <= lB;
      uint4 uA, uB;
      if (fA) uA = *reinterpret_cast<const uint4*>(eA + i4);
      if (fB) uB = *reinterpret_cast<const uint4*>(eB + i4);
      float a0, a1, a2, a3, c0, c1, c2, c3;
      if (fA) {
        a0 = val[uA.x >> SHIFT]; a1 = val[uA.y >> SHIFT];
        a2 = val[uA.z >> SHIFT]; a3 = val[uA.w >> SHIFT];
      }
      if (fB) {
        c0 = val[uB.x >> SHIFT]; c1 = val[uB.y >> SHIFT];
        c2 = val[uB.z >> SHIFT]; c3 = val[uB.w >> SHIFT];
      }
      if (fA) {
        atomicAdd(&bins[uA.x & MASK], a0);
        atomicAdd(&bins[uA.y & MASK], a1);
        atomicAdd(&bins[uA.z & MASK], a2);
        atomicAdd(&bins[uA.w & MASK], a3);
      }
      if (fB) {
        atomicAdd(&bins[uB.x & MASK], c0);
        atomicAdd(&bins[uB.y & MASK], c1);
        atomicAdd(&bins[uB.z & MASK], c2);
        atomicAdd(&bins[uB.w & MASK], c3);
      }
    }
    // cooperative tail over these 8 segs' [st, l) regions
    TAILPRE
    for (int t = lane; t < qT; t += 64) {
      TAILSEL
      unsigned v = es[st + t - pr];
      atomicAdd(&bins[v & MASK], val[v >> SHIFT]);
    }
  }
  __syncthreads();
  float* my = part + ((size_t)ks * NB + p) * RANGE;
  for (int i = tid; i < RANGE; i += 256) my[i] = bins[i];
}

// ---- K5: reduce s partials; layer1 epilogue + relu + dropout2 + W2 dot -----
__global__ __launch_bounds__(256) void k_node2(
    const float* __restrict__ part, const float* __restrict__ dinv,
    const float* __restrict__ W1, const float* __restrict__ b1,
    const float* __restrict__ W2, float* __restrict__ z2,
    int NB, int n, unsigned k2a, unsigned k2b) {
  int i = blockIdx.x * blockDim.x + threadIdx.x;
  if (i >= n) return;
  const int p = i >> SHIFT, r = i & MASK;
  float s = 0.0f;
  for (int b = 0; b < KS; ++b)
    s += part[((size_t)b * NB + p) * RANGE + r];
  float t = s * dinv[i];
  float z = 0.0f;
  unsigned base = (unsigned)i * 16u;
#pragma unroll
  for (int c = 0; c < 16; ++c) {
    float h = W1[c] * t + b1[c];
    h = fmaxf(h, 0.0f);
    unsigned o0, o1;
    threefry2x32(k2a, k2b, 0u, base + (unsigned)c, o0, o1);
    float u = u01_from_bits(o0 ^ o1);
    float hd = (u < KEEP_P) ? (h / KEEP_P) : 0.0f;
    z += hd * W2[c];
  }
  z2[i] = z * dinv[i];   // dinv[dst] factor applied in k_final
}

// ---- K7: final combine: out = b2 + dinv * sum(partials) --------------------
__global__ __launch_bounds__(256) void k_final(
    const float* __restrict__ part, const float* __restrict__ dinv,
    const float* __restrict__ b2, float* __restrict__ out,
    int NB, int n) {
  int i = blockIdx.x * blockDim.x + threadIdx.x;
  if (i >= n) return;
  const int p = i >> SHIFT, r = i & MASK;
  float s = 0.0f;
  for (int b = 0; b < KS; ++b)
    s += part[((size_t)b * NB + p) * RANGE + r];
  out[i] = b2[0] + dinv[i] * s;
}

extern "C" void kernel_launch(void* const* d_in, const int* in_sizes, int n_in,
                              void* d_out, int out_size, void* d_ws, size_t ws_size,
                              hipStream_t stream) {
  const float* x  = (const float*)d_in[0];
  const int* edge = (const int*)d_in[1];   // [2, E] int32
  const float* W1 = (const float*)d_in[2]; // [1,16]
  const float* b1 = (const float*)d_in[3]; // [16]
  const float* W2 = (const float*)d_in[4]; // [16,1]
  const float* b2 = (const float*)d_in[5]; // [1]
  float* out = (float*)d_out;              // [N,1] f32

  const int N = in_sizes[0];
  const int E = in_sizes[1] / 2;
  const int* src = edge;
  const int* dst = edge + E;

  const int NP = (N + 255) & ~255;
  const int NB = (N + RANGE - 1) / RANGE;   // 49 for N=100K (<= NBMAX)

  // ws layout: [slots NB*BPC*CAP u32][cnt BPC*NB u32]
  //            [part KS*NB*RANGE f32 (aliases deg u16 partials)][dinv][y][z2]
  const size_t cnt_sz  = (size_t)BPC * NB * 4;
  const size_t part_sz = (size_t)KS * NB * RANGE * 4;
  const size_t small_sz = (size_t)3 * NP * 4;
  size_t fixed = cnt_sz + part_sz + small_sz + 512;
  size_t avail = ws_size > fixed ? ws_size - fixed : 0;
  int CAP = (int)(avail / ((size_t)NB * BPC * 4));
  CAP &= ~3;                  // 16B-aligned slot starts for uint4 loads
  if (CAP > 120) CAP = 120;   // lam=64, +7sigma (R19 proved ws >= ~100MB)
  if (CAP < 104) CAP = 104;   // ws guard (should not trigger)

  char* w = (char*)d_ws;
  unsigned* slots = (unsigned*)w;        w += (size_t)NB * BPC * CAP * 4;
  unsigned* cnt   = (unsigned*)w;        w += cnt_sz;
  w = (char*)(((uintptr_t)w + 255) & ~(uintptr_t)255);
  float* part_f = (float*)w;
  unsigned short* part16 = (unsigned short*)w;  // aliased (deg phase ends first)
  w += part_sz;
  float* dinv = (float*)w;
  float* y    = dinv + NP;
  float* z2   = y + NP;

  // Dropout keys: foldlike split(key(42)) under partitionable threefry.
  unsigned k1a, k1b, k2a, k2b;
  threefry2x32(0u, 42u, 0u, 0u, k1a, k1b);
  threefry2x32(0u, 42u, 0u, 1u, k2a, k2b);

  const int e4 = E >> 2;
  const int gN = (N + 255) / 256;

  k_part <<<BPC, 256, 0, stream>>>(src, dst, slots, cnt, NB, CAP, e4, E);
  k_deg2 <<<dim3(KS, NB), 256, 0, stream>>>(slots, cnt, part16, NB, CAP);
  k_node1<<<gN, 256, 0, stream>>>(x, part16, dinv, y, NB, N, k1a, k1b);
  k_scat <<<dim3(KS, NB), 256, 0, stream>>>(slots, cnt, y, part_f, NB, CAP);
  k_node2<<<gN, 256, 0, stream>>>(part_f, dinv, W1, b1, W2, z2, NB, N, k2a, k2b);
  k_scat <<<dim3(KS, NB), 256, 0, stream>>>(slots, cnt, z2, part_f, NB, CAP);
  k_final<<<gN, 256, 0, stream>>>(part_f, dinv, b2, out, NB, N);
}